// Round 1
// baseline (551.286 us; speedup 1.0000x reference)
//
#include <hip/hip_runtime.h>

// ---------------------------------------------------------------------------
// CellVGAE GCN encoder: x -> GCN(512,128)+ReLU -> GCN(128,128)+ReLU
//                         -> {GCN(128,64) mean, GCN(128,64) log_std}
// Round 6:
//  - GEMM rewritten barrier-free + LDS-free: A and B MFMA fragments are
//    loaded directly from global memory (A: HBM/L3 stream, reg double-
//    buffered 2 K-steps deep; B: L2-resident, loaded just-in-time).
//    bf16 hi/lo split done in-register between B-issue and MFMA.
//    Removes 32 barrier-drains per block (was 2 per K-step) and all LDS
//    bank traffic. MFMA order identical to round 5 => identical numerics.
// ---------------------------------------------------------------------------

using u16 = unsigned short;
typedef __attribute__((ext_vector_type(8))) short short8;
typedef __attribute__((ext_vector_type(4))) float f32x4;

__device__ __forceinline__ void split_bf16(float f, u16& hi, u16& lo) {
    unsigned b = __float_as_uint(f);
    hi = (u16)(b >> 16);
    float rem = f - __uint_as_float(b & 0xFFFF0000u);
    lo = (u16)(__float_as_uint(rem) >> 16);
}

// Block-wide mode detect: 1 = int64 edge_index, 0 = int32.
__device__ __forceinline__ int block_mode(const int* __restrict__ ew, int* sflag) {
    if (threadIdx.x == 0) *sflag = 0;
    __syncthreads();
    if (ew[2 * (int)threadIdx.x + 1] != 0) atomicOr(sflag, 1);
    __syncthreads();
    return *sflag ? 0 : 1;
}

// ---- degree count (mode detect inlined) -----------------------------------
__global__ void deg_kernel(const int* __restrict__ ew, int* __restrict__ deg, int E) {
    __shared__ int sflag;
    int mode = block_mode(ew, &sflag);
    int e = blockIdx.x * blockDim.x + threadIdx.x;
    if (e >= E) return;
    int d = mode ? ew[2 * E + 2 * e] : ew[E + e];
    atomicAdd(&deg[d], 1);
}

// ---- exclusive scan over deg -> rowptr, fused dis = rsqrt(deg+1) ----------
__global__ void scan_block_kernel(const int* __restrict__ deg, int* __restrict__ rowptr,
                                  int* __restrict__ aux, float* __restrict__ dis, int N) {
    __shared__ int s[256];
    int i = blockIdx.x * 256 + threadIdx.x;
    int v = (i < N) ? deg[i] : 0;
    if (i < N) dis[i] = rsqrtf((float)v + 1.0f);
    s[threadIdx.x] = v;
    __syncthreads();
    for (int off = 1; off < 256; off <<= 1) {
        int t = (threadIdx.x >= off) ? s[threadIdx.x - off] : 0;
        __syncthreads();
        s[threadIdx.x] += t;
        __syncthreads();
    }
    if (i < N) rowptr[i] = s[threadIdx.x] - v;
    if (threadIdx.x == 255) aux[blockIdx.x] = s[255];
}

__global__ void scan_aux_kernel(int* __restrict__ aux, int nb) {
    __shared__ int s[256];
    int i = threadIdx.x;
    int v = (i < nb) ? aux[i] : 0;
    s[i] = v;
    __syncthreads();
    for (int off = 1; off < 256; off <<= 1) {
        int t = (i >= off) ? s[i - off] : 0;
        __syncthreads();
        s[i] += t;
        __syncthreads();
    }
    if (i < nb) aux[i] = s[i] - v;
}

__global__ void add_offsets_kernel(int* __restrict__ rowptr, const int* __restrict__ aux,
                                   int N, int E) {
    int i = blockIdx.x * 256 + threadIdx.x;
    if (i < N) rowptr[i] += aux[i >> 8];
    if (i == 0) rowptr[N] = E;
}

// ---- CSR fill (mode detect inlined) ---------------------------------------
__global__ void fill_csr_kernel(const int* __restrict__ ew,
                                const int* __restrict__ rowptr, int* __restrict__ cursor,
                                int* __restrict__ csr_src, int E) {
    __shared__ int sflag;
    int mode = block_mode(ew, &sflag);
    int e = blockIdx.x * blockDim.x + threadIdx.x;
    if (e >= E) return;
    int s = mode ? ew[2 * e] : ew[e];
    int d = mode ? ew[2 * E + 2 * e] : ew[E + e];
    int pos = rowptr[d] + atomicAdd(&cursor[d], 1);
    csr_src[pos] = s;
}

// ---- all weight transposed-splits in one kernel ---------------------------
__global__ void conv_all_kernel(const float* __restrict__ W1, const float* __restrict__ W2,
                                const float* __restrict__ Wm, const float* __restrict__ Ws,
                                u16* __restrict__ W1t_hi, u16* __restrict__ W1t_lo,
                                u16* __restrict__ W2t_hi, u16* __restrict__ W2t_lo,
                                u16* __restrict__ Wct_hi, u16* __restrict__ Wct_lo) {
    int idx = blockIdx.x * 256 + threadIdx.x;
    u16 h, l;
    if (idx < 65536) {                 // W1: 512x128 -> [128][512]
        int k = idx >> 7, n = idx & 127;
        split_bf16(W1[idx], h, l);
        W1t_hi[n * 512 + k] = h;
        W1t_lo[n * 512 + k] = l;
    } else if (idx < 81920) {          // W2: 128x128 -> [128][128]
        int t = idx - 65536;
        int k = t >> 7, n = t & 127;
        split_bf16(W2[t], h, l);
        W2t_hi[n * 128 + k] = h;
        W2t_lo[n * 128 + k] = l;
    } else if (idx < 98304) {          // [Wm|Ws]: 128x128 -> [128][128]
        int t = idx - 81920;
        int k = t >> 7, j = t & 127;
        float f = (j < 64) ? Wm[k * 64 + j] : Ws[k * 64 + (j - 64)];
        split_bf16(f, h, l);
        Wct_hi[j * 128 + k] = h;
        Wct_lo[j * 128 + k] = l;
    }
}

// ---- MFMA GEMM: C[N x 128] = A[N x K] @ B[K x 128] (B given split+T) ------
// Barrier-free / LDS-free. One wave owns a 32-row x 64-col output tile.
// Fragment layout for mfma_f32_16x16x32_bf16 (verified round-5 mapping):
//   A-frag lane L: row (L&15), k = (L>>4)*8 .. +8   -> direct global load
//   B-frag lane L: col (L&15), k = (L>>4)*8 .. +8   -> direct load from Bt
//   C/D: col = lane&15, row = (lane>>4)*4 + reg
// A raw fp32 is reg double-buffered two K-steps ahead (HBM latency); B is
// loaded just-in-time from L2 (all blocks share the same 256 KB of Bt).
__global__ __launch_bounds__(256) void gemm_mfma(const float* __restrict__ A,
                                                 const u16* __restrict__ Bt_hi,
                                                 const u16* __restrict__ Bt_lo,
                                                 float* __restrict__ C,
                                                 int N, int K) {
    const int tid = threadIdx.x;
    const int w = tid >> 6, lane = tid & 63;
    const int m16 = lane & 15, quad = lane >> 4;

    const int nrt = (N + 31) >> 5;            // 32-row tiles
    const int wtile = blockIdx.x * 4 + w;
    if (wtile >= 2 * nrt) return;
    const int rt = wtile >> 1;                // row tile
    const int c0 = (wtile & 1) << 6;          // col half: 0 or 64
    const int row0 = rt << 5;

    // clamped fragment rows (garbage rows only feed outputs we never store)
    int r0 = row0 + m16;      if (r0 > N - 1) r0 = N - 1;
    int r1 = row0 + 16 + m16; if (r1 > N - 1) r1 = N - 1;
    const float* ap0 = A + (size_t)r0 * K + quad * 8;
    const float* ap1 = A + (size_t)r1 * K + quad * 8;
    const u16* bph = Bt_hi + (size_t)(c0 + m16) * K + quad * 8;
    const u16* bpl = Bt_lo + (size_t)(c0 + m16) * K + quad * 8;
    const size_t bstr = (size_t)16 * K;       // col-tile stride (u16 elems)

    f32x4 acc[2][4];
#pragma unroll
    for (int i = 0; i < 2; ++i)
#pragma unroll
        for (int j = 0; j < 4; ++j) acc[i][j] = (f32x4)0.f;

    f32x4 x0, x1, x2, x3;                     // A raw, buffer X
    f32x4 y0, y1, y2, y3;                     // A raw, buffer Y

    auto lda = [&](f32x4& v0, f32x4& v1, f32x4& v2, f32x4& v3, int kk) {
        const float* p0 = ap0 + kk * 32;
        const float* p1 = ap1 + kk * 32;
        v0 = *(const f32x4*)p0;
        v1 = *(const f32x4*)(p0 + 4);
        v2 = *(const f32x4*)p1;
        v3 = *(const f32x4*)(p1 + 4);
    };
    auto cvt = [&](const f32x4& v0, const f32x4& v1, short8& h, short8& l) {
#pragma unroll
        for (int q = 0; q < 4; ++q) {
            u16 hh, ll;
            split_bf16(v0[q], hh, ll);
            h[q] = (short)hh;
            l[q] = (short)ll;
            split_bf16(v1[q], hh, ll);
            h[4 + q] = (short)hh;
            l[4 + q] = (short)ll;
        }
    };
    // one K-step: issue B loads early, convert A (covers B L2 latency),
    // issue the next-next A prefetch into the freed raw regs, then MFMA.
    auto step = [&](f32x4& v0, f32x4& v1, f32x4& v2, f32x4& v3,
                    int kk, int kpre, bool pre) {
        short8 bh[4], bl[4];
#pragma unroll
        for (int j = 0; j < 4; ++j) {
            bh[j] = *(const short8*)(bph + bstr * j + kk * 32);
            bl[j] = *(const short8*)(bpl + bstr * j + kk * 32);
        }
        short8 ah[2], al[2];
        cvt(v0, v1, ah[0], al[0]);
        cvt(v2, v3, ah[1], al[1]);
        if (pre) lda(v0, v1, v2, v3, kpre);
#pragma unroll
        for (int i = 0; i < 2; ++i)
#pragma unroll
            for (int j = 0; j < 4; ++j) {
                acc[i][j] = __builtin_amdgcn_mfma_f32_16x16x32_bf16(
                    ah[i], bh[j], acc[i][j], 0, 0, 0);
                acc[i][j] = __builtin_amdgcn_mfma_f32_16x16x32_bf16(
                    ah[i], bl[j], acc[i][j], 0, 0, 0);
                acc[i][j] = __builtin_amdgcn_mfma_f32_16x16x32_bf16(
                    al[i], bh[j], acc[i][j], 0, 0, 0);
            }
    };

    const int ksteps = K >> 5;                // 16 (K=512) or 4 (K=128)
    lda(x0, x1, x2, x3, 0);
    lda(y0, y1, y2, y3, 1);
    int ks = 0;
    for (; ks + 2 < ksteps; ks += 2) {
        step(x0, x1, x2, x3, ks, ks + 2, true);
        step(y0, y1, y2, y3, ks + 1, ks + 3, true);
    }
    step(x0, x1, x2, x3, ks, 0, false);
    step(y0, y1, y2, y3, ks + 1, 0, false);

    // epilogue: C/D layout col=lane&15, row=quad*4+reg
#pragma unroll
    for (int i = 0; i < 2; ++i) {
#pragma unroll
        for (int r = 0; r < 4; ++r) {
            int gr = row0 + i * 16 + quad * 4 + r;
            if (gr < N) {
#pragma unroll
                for (int j = 0; j < 4; ++j)
                    C[(size_t)gr * 128 + c0 + j * 16 + m16] = acc[i][j][r];
            }
        }
    }
}

// ---- propagate (one wave per node, 128 feats = 2/lane), unroll x8 ---------
__global__ __launch_bounds__(256) void propagate_kernel(
    const float* __restrict__ h, const int* __restrict__ rowptr,
    const int* __restrict__ csr_src, const float* __restrict__ dis,
    const float* __restrict__ bias, float* __restrict__ out, int N, int do_relu) {
    int wave = (blockIdx.x * 256 + threadIdx.x) >> 6;
    int lane = threadIdx.x & 63;
    if (wave >= N) return;
    int v = wave;
    int f = lane * 2;
    float dv = dis[v];
    float ax = 0.f, ay = 0.f;
    int beg = rowptr[v], end = rowptr[v + 1];
    int i = beg;
    for (; i + 8 <= end; i += 8) {
        int s[8];
        float ww[8];
        float2 g[8];
#pragma unroll
        for (int u = 0; u < 8; ++u) s[u] = csr_src[i + u];
#pragma unroll
        for (int u = 0; u < 8; ++u) ww[u] = dis[s[u]];
#pragma unroll
        for (int u = 0; u < 8; ++u) g[u] = *(const float2*)&h[(size_t)s[u] * 128 + f];
#pragma unroll
        for (int u = 0; u < 8; ++u) {
            float t = ww[u] * dv;
            ax += t * g[u].x;
            ay += t * g[u].y;
        }
    }
    if (i + 4 <= end) {
        int s[4];
        float ww[4];
        float2 g[4];
#pragma unroll
        for (int u = 0; u < 4; ++u) s[u] = csr_src[i + u];
#pragma unroll
        for (int u = 0; u < 4; ++u) ww[u] = dis[s[u]];
#pragma unroll
        for (int u = 0; u < 4; ++u) g[u] = *(const float2*)&h[(size_t)s[u] * 128 + f];
#pragma unroll
        for (int u = 0; u < 4; ++u) {
            float t = ww[u] * dv;
            ax += t * g[u].x;
            ay += t * g[u].y;
        }
        i += 4;
    }
    for (; i < end; ++i) {
        int s = csr_src[i];
        float ws = dis[s] * dv;
        float2 g = *(const float2*)&h[(size_t)s * 128 + f];
        ax += ws * g.x;
        ay += ws * g.y;
    }
    float2 hv = *(const float2*)&h[(size_t)v * 128 + f];
    ax += dv * dv * hv.x;
    ay += dv * dv * hv.y;
    ax += bias[f];
    ay += bias[f + 1];
    if (do_relu) { ax = fmaxf(ax, 0.f); ay = fmaxf(ay, 0.f); }
    *(float2*)&out[(size_t)v * 128 + f] = make_float2(ax, ay);
}

// ---- final propagate: split into z_mean / z_log_std -----------------------
__global__ __launch_bounds__(256) void propagate_final_kernel(
    const float* __restrict__ h, const int* __restrict__ rowptr,
    const int* __restrict__ csr_src, const float* __restrict__ dis,
    const float* __restrict__ bm, const float* __restrict__ bs,
    float* __restrict__ out, int N) {
    int wave = (blockIdx.x * 256 + threadIdx.x) >> 6;
    int lane = threadIdx.x & 63;
    if (wave >= N) return;
    int v = wave;
    int f = lane * 2;
    float dv = dis[v];
    float ax = 0.f, ay = 0.f;
    int beg = rowptr[v], end = rowptr[v + 1];
    int i = beg;
    for (; i + 8 <= end; i += 8) {
        int s[8];
        float ww[8];
        float2 g[8];
#pragma unroll
        for (int u = 0; u < 8; ++u) s[u] = csr_src[i + u];
#pragma unroll
        for (int u = 0; u < 8; ++u) ww[u] = dis[s[u]];
#pragma unroll
        for (int u = 0; u < 8; ++u) g[u] = *(const float2*)&h[(size_t)s[u] * 128 + f];
#pragma unroll
        for (int u = 0; u < 8; ++u) {
            float t = ww[u] * dv;
            ax += t * g[u].x;
            ay += t * g[u].y;
        }
    }
    if (i + 4 <= end) {
        int s[4];
        float ww[4];
        float2 g[4];
#pragma unroll
        for (int u = 0; u < 4; ++u) s[u] = csr_src[i + u];
#pragma unroll
        for (int u = 0; u < 4; ++u) ww[u] = dis[s[u]];
#pragma unroll
        for (int u = 0; u < 4; ++u) g[u] = *(const float2*)&h[(size_t)s[u] * 128 + f];
#pragma unroll
        for (int u = 0; u < 4; ++u) {
            float t = ww[u] * dv;
            ax += t * g[u].x;
            ay += t * g[u].y;
        }
        i += 4;
    }
    for (; i < end; ++i) {
        int s = csr_src[i];
        float ws = dis[s] * dv;
        float2 g = *(const float2*)&h[(size_t)s * 128 + f];
        ax += ws * g.x;
        ay += ws * g.y;
    }
    float2 hv = *(const float2*)&h[(size_t)v * 128 + f];
    ax += dv * dv * hv.x;
    ay += dv * dv * hv.y;
    if (f < 64) {
        *(float2*)&out[(size_t)v * 64 + f] = make_float2(ax + bm[f], ay + bm[f + 1]);
    } else {
        int g = f - 64;
        *(float2*)&out[(size_t)N * 64 + (size_t)v * 64 + g] =
            make_float2(ax + bs[g], ay + bs[g + 1]);
    }
}

extern "C" void kernel_launch(void* const* d_in, const int* in_sizes, int n_in,
                              void* d_out, int out_size, void* d_ws, size_t ws_size,
                              hipStream_t stream) {
    const float* x  = (const float*)d_in[0];
    const int*   ew = (const int*)d_in[1];
    const float* W1 = (const float*)d_in[2];
    const float* b1 = (const float*)d_in[3];
    const float* W2 = (const float*)d_in[4];
    const float* b2 = (const float*)d_in[5];
    const float* Wm = (const float*)d_in[6];
    const float* bm = (const float*)d_in[7];
    const float* Ws = (const float*)d_in[8];
    const float* bs = (const float*)d_in[9];
    float* out = (float*)d_out;

    const int IN = 512, H = 128;
    const int N = in_sizes[0] / IN;     // 50000
    const int E = in_sizes[1] / 2;      // 800000

    // ---- workspace: ~55.6 MB total (< proven-safe 58.47 MB) ----------------
    char* base = (char*)d_ws;
    size_t off = 0;
    auto alloc = [&](size_t bytes) -> char* {
        char* p = base + off;
        off = (off + bytes + 255) & ~(size_t)255;
        return p;
    };
    char*  degcur  = (char*) alloc(400384);             // deg + cursor (zeroed)
    float* dis     = (float*)alloc((size_t)N * 4);
    int*   rowptr  = (int*)  alloc((size_t)(N + 1) * 4);
    int*   aux     = (int*)  alloc(256 * 4);
    int*   csr_src = (int*)  alloc((size_t)E * 4);
    u16*   W1t_hi  = (u16*)  alloc((size_t)IN * H * 2);
    u16*   W1t_lo  = (u16*)  alloc((size_t)IN * H * 2);
    u16*   W2t_hi  = (u16*)  alloc((size_t)H * H * 2);
    u16*   W2t_lo  = (u16*)  alloc((size_t)H * H * 2);
    u16*   Wct_hi  = (u16*)  alloc((size_t)H * H * 2);
    u16*   Wct_lo  = (u16*)  alloc((size_t)H * H * 2);
    float* hA      = (float*)alloc((size_t)N * H * 4);
    float* hB      = (float*)alloc((size_t)N * H * 4);
    (void)ws_size; (void)n_in; (void)out_size;

    int* deg    = (int*)degcur;
    int* cursor = (int*)(degcur + 200192);

    hipMemsetAsync(degcur, 0, 400384, stream);

    const int eblocks = (E + 255) / 256;
    const int nblocks = (N + 255) / 256;

    conv_all_kernel<<<(98304 + 255) / 256, 256, 0, stream>>>(
        W1, W2, Wm, Ws, W1t_hi, W1t_lo, W2t_hi, W2t_lo, Wct_hi, Wct_lo);
    deg_kernel<<<eblocks, 256, 0, stream>>>(ew, deg, E);
    scan_block_kernel<<<nblocks, 256, 0, stream>>>(deg, rowptr, aux, dis, N);
    scan_aux_kernel<<<1, 256, 0, stream>>>(aux, nblocks);
    add_offsets_kernel<<<nblocks, 256, 0, stream>>>(rowptr, aux, N, E);
    fill_csr_kernel<<<eblocks, 256, 0, stream>>>(ew, rowptr, cursor, csr_src, E);

    // barrier-free GEMM: one wave per 32x64 output tile
    const int wtiles = 2 * ((N + 31) / 32);
    const int gblocks = (wtiles + 3) / 4;
    const int pblocks = (N * 64 + 255) / 256;

    gemm_mfma<<<gblocks, 256, 0, stream>>>(x, W1t_hi, W1t_lo, hA, N, IN);
    propagate_kernel<<<pblocks, 256, 0, stream>>>(hA, rowptr, csr_src, dis,
                                                  b1, hB, N, 1);
    gemm_mfma<<<gblocks, 256, 0, stream>>>(hB, W2t_hi, W2t_lo, hA, N, H);
    propagate_kernel<<<pblocks, 256, 0, stream>>>(hA, rowptr, csr_src, dis,
                                                  b2, hB, N, 1);
    gemm_mfma<<<gblocks, 256, 0, stream>>>(hB, Wct_hi, Wct_lo, hA, N, H);
    propagate_final_kernel<<<pblocks, 256, 0, stream>>>(hA, rowptr, csr_src, dis,
                                                        bm, bs, out, N);
}

// Round 2
// 521.972 us; speedup vs baseline: 1.0562x; 1.0562x over previous
//
#include <hip/hip_runtime.h>

// ---------------------------------------------------------------------------
// CellVGAE GCN encoder: x -> GCN(512,128)+ReLU -> GCN(128,128)+ReLU
//                         -> {GCN(128,64) mean, GCN(128,64) log_std}
// Round 7:
//  - GEMM hybrid: B staged via LDS (round-5 fragment-order map, proven
//    conflict-free) but DOUBLE-BUFFERED -> ONE barrier per K-step (was 2).
//    A fragments loaded direct-to-register (round-6 path, per-lane rows)
//    with 2-step prefetch; B global loads 1 step ahead (L2-resident).
//    Round 6 failed because B per-lane gathers shattered into per-line
//    transactions (TA-bound: MfmaUtil 7.6%, HBM 0.8 TB/s); B->LDS restores
//    coalescing while keeping the barrier reduction.
//  - MFMA order identical to rounds 5/6 => identical numerics.
// ---------------------------------------------------------------------------

using u16 = unsigned short;
typedef __attribute__((ext_vector_type(8))) short short8;
typedef __attribute__((ext_vector_type(4))) float f32x4;

__device__ __forceinline__ void split_bf16(float f, u16& hi, u16& lo) {
    unsigned b = __float_as_uint(f);
    hi = (u16)(b >> 16);
    float rem = f - __uint_as_float(b & 0xFFFF0000u);
    lo = (u16)(__float_as_uint(rem) >> 16);
}

// Block-wide mode detect: 1 = int64 edge_index, 0 = int32.
__device__ __forceinline__ int block_mode(const int* __restrict__ ew, int* sflag) {
    if (threadIdx.x == 0) *sflag = 0;
    __syncthreads();
    if (ew[2 * (int)threadIdx.x + 1] != 0) atomicOr(sflag, 1);
    __syncthreads();
    return *sflag ? 0 : 1;
}

// ---- degree count (mode detect inlined) -----------------------------------
__global__ void deg_kernel(const int* __restrict__ ew, int* __restrict__ deg, int E) {
    __shared__ int sflag;
    int mode = block_mode(ew, &sflag);
    int e = blockIdx.x * blockDim.x + threadIdx.x;
    if (e >= E) return;
    int d = mode ? ew[2 * E + 2 * e] : ew[E + e];
    atomicAdd(&deg[d], 1);
}

// ---- exclusive scan over deg -> rowptr, fused dis = rsqrt(deg+1) ----------
__global__ void scan_block_kernel(const int* __restrict__ deg, int* __restrict__ rowptr,
                                  int* __restrict__ aux, float* __restrict__ dis, int N) {
    __shared__ int s[256];
    int i = blockIdx.x * 256 + threadIdx.x;
    int v = (i < N) ? deg[i] : 0;
    if (i < N) dis[i] = rsqrtf((float)v + 1.0f);
    s[threadIdx.x] = v;
    __syncthreads();
    for (int off = 1; off < 256; off <<= 1) {
        int t = (threadIdx.x >= off) ? s[threadIdx.x - off] : 0;
        __syncthreads();
        s[threadIdx.x] += t;
        __syncthreads();
    }
    if (i < N) rowptr[i] = s[threadIdx.x] - v;
    if (threadIdx.x == 255) aux[blockIdx.x] = s[255];
}

__global__ void scan_aux_kernel(int* __restrict__ aux, int nb) {
    __shared__ int s[256];
    int i = threadIdx.x;
    int v = (i < nb) ? aux[i] : 0;
    s[i] = v;
    __syncthreads();
    for (int off = 1; off < 256; off <<= 1) {
        int t = (i >= off) ? s[i - off] : 0;
        __syncthreads();
        s[i] += t;
        __syncthreads();
    }
    if (i < nb) aux[i] = s[i] - v;
}

__global__ void add_offsets_kernel(int* __restrict__ rowptr, const int* __restrict__ aux,
                                   int N, int E) {
    int i = blockIdx.x * 256 + threadIdx.x;
    if (i < N) rowptr[i] += aux[i >> 8];
    if (i == 0) rowptr[N] = E;
}

// ---- CSR fill (mode detect inlined) ---------------------------------------
__global__ void fill_csr_kernel(const int* __restrict__ ew,
                                const int* __restrict__ rowptr, int* __restrict__ cursor,
                                int* __restrict__ csr_src, int E) {
    __shared__ int sflag;
    int mode = block_mode(ew, &sflag);
    int e = blockIdx.x * blockDim.x + threadIdx.x;
    if (e >= E) return;
    int s = mode ? ew[2 * e] : ew[e];
    int d = mode ? ew[2 * E + 2 * e] : ew[E + e];
    int pos = rowptr[d] + atomicAdd(&cursor[d], 1);
    csr_src[pos] = s;
}

// ---- all weight transposed-splits in one kernel ---------------------------
__global__ void conv_all_kernel(const float* __restrict__ W1, const float* __restrict__ W2,
                                const float* __restrict__ Wm, const float* __restrict__ Ws,
                                u16* __restrict__ W1t_hi, u16* __restrict__ W1t_lo,
                                u16* __restrict__ W2t_hi, u16* __restrict__ W2t_lo,
                                u16* __restrict__ Wct_hi, u16* __restrict__ Wct_lo) {
    int idx = blockIdx.x * 256 + threadIdx.x;
    u16 h, l;
    if (idx < 65536) {                 // W1: 512x128 -> [128][512]
        int k = idx >> 7, n = idx & 127;
        split_bf16(W1[idx], h, l);
        W1t_hi[n * 512 + k] = h;
        W1t_lo[n * 512 + k] = l;
    } else if (idx < 81920) {          // W2: 128x128 -> [128][128]
        int t = idx - 65536;
        int k = t >> 7, n = t & 127;
        split_bf16(W2[t], h, l);
        W2t_hi[n * 128 + k] = h;
        W2t_lo[n * 128 + k] = l;
    } else if (idx < 98304) {          // [Wm|Ws]: 128x128 -> [128][128]
        int t = idx - 81920;
        int k = t >> 7, j = t & 127;
        float f = (j < 64) ? Wm[k * 64 + j] : Ws[k * 64 + (j - 64)];
        split_bf16(f, h, l);
        Wct_hi[j * 128 + k] = h;
        Wct_lo[j * 128 + k] = l;
    }
}

// ---- MFMA GEMM: C[N x 128] = A[N x K] @ B[K x 128] (B given split+T) ------
// Hybrid: B via double-buffered LDS (fragment-order layout, tile stride
// 1040 B), ONE barrier per K-step; A direct per-lane loads, 2-step reg
// double-buffer. Fragment layout (mfma_f32_16x16x32_bf16, verified):
//   A/B-frag lane L: row/col (L&15), k = (L>>4)*8 .. +8
//   C/D: col = lane&15, row = (lane>>4)*4 + reg
#define TILE_OFF(t) ((t) * 520)

__global__ __launch_bounds__(256) void gemm_mfma(const float* __restrict__ A,
                                                 const u16* __restrict__ Bt_hi,
                                                 const u16* __restrict__ Bt_lo,
                                                 float* __restrict__ C,
                                                 int N, int K) {
    __shared__ __align__(16) u16 BsH[2][8 * 520], BsL[2][8 * 520];  // 33.3 KB

    const int tid = threadIdx.x;
    const int w = tid >> 6, lane = tid & 63;
    const int m16 = lane & 15, quad = lane >> 4;

    const int row0 = blockIdx.x * 64;          // block row base (64 rows)
    const int R = (w >> 1) * 32;               // wave row sub-tile
    const int c0 = (w & 1) << 6;               // wave col half
    const int btile = (w & 1) * 4;             // B col-tile base for frags

    // B staging map (round-5 proven, conflict-free): thread -> (col, khalf)
    const int s_bc = tid >> 1;                 // col 0..127
    const int s_bk = (tid & 1) * 16;           // k offset 0 or 16
    const int b_q0 = (tid & 1) * 2;
    const int b_dst0 = TILE_OFF(s_bc >> 4) + ((s_bc & 15) + 16 * (b_q0 + 0)) * 8;
    const int b_dst1 = TILE_OFF(s_bc >> 4) + ((s_bc & 15) + 16 * (b_q0 + 1)) * 8;
    const u16* bph = Bt_hi + (size_t)s_bc * K + s_bk;
    const u16* bpl = Bt_lo + (size_t)s_bc * K + s_bk;

    // A direct fragment rows (round-6 proven); clamped rows feed only
    // outputs the epilogue never stores.
    int r0 = row0 + R + m16;      if (r0 > N - 1) r0 = N - 1;
    int r1 = row0 + R + 16 + m16; if (r1 > N - 1) r1 = N - 1;
    const float* ap0 = A + (size_t)r0 * K + quad * 8;
    const float* ap1 = A + (size_t)r1 * K + quad * 8;

    f32x4 acc[2][4];
#pragma unroll
    for (int i = 0; i < 2; ++i)
#pragma unroll
        for (int j = 0; j < 4; ++j) acc[i][j] = (f32x4)0.f;

    f32x4 x0, x1, x2, x3;                      // A raw, buffer X (even ks)
    f32x4 y0, y1, y2, y3;                      // A raw, buffer Y (odd ks)
    short8 rbh0, rbh1, rbl0, rbl1;             // B staging regs

    auto ldb = [&](int kk) {
        rbh0 = *(const short8*)(bph + kk * 32);
        rbh1 = *(const short8*)(bph + kk * 32 + 8);
        rbl0 = *(const short8*)(bpl + kk * 32);
        rbl1 = *(const short8*)(bpl + kk * 32 + 8);
    };
    auto stb = [&](int buf) {
        *(short8*)&BsH[buf][b_dst0] = rbh0;
        *(short8*)&BsH[buf][b_dst1] = rbh1;
        *(short8*)&BsL[buf][b_dst0] = rbl0;
        *(short8*)&BsL[buf][b_dst1] = rbl1;
    };
    auto lda = [&](f32x4& v0, f32x4& v1, f32x4& v2, f32x4& v3, int kk) {
        const float* p0 = ap0 + kk * 32;
        const float* p1 = ap1 + kk * 32;
        v0 = *(const f32x4*)p0;
        v1 = *(const f32x4*)(p0 + 4);
        v2 = *(const f32x4*)p1;
        v3 = *(const f32x4*)(p1 + 4);
    };
    auto cvt = [&](const f32x4& v0, const f32x4& v1, short8& h, short8& l) {
#pragma unroll
        for (int q = 0; q < 4; ++q) {
            u16 hh, ll;
            split_bf16(v0[q], hh, ll);
            h[q] = (short)hh;
            l[q] = (short)ll;
            split_bf16(v1[q], hh, ll);
            h[4 + q] = (short)hh;
            l[4 + q] = (short)ll;
        }
    };

    const int ksteps = K >> 5;                 // 16 (K=512) or 4 (K=128)
    ldb(0);
    lda(x0, x1, x2, x3, 0);
    lda(y0, y1, y2, y3, 1);
    stb(0);
    ldb(1);

    for (int ks = 0; ks < ksteps; ++ks) {
        const int buf = ks & 1;
        __syncthreads();                        // buf ready; old reads done
        if (ks + 1 < ksteps) stb(buf ^ 1);      // write next tile
        if (ks + 2 < ksteps) ldb(ks + 2);       // refill B regs (1-step cover)

        short8 fbh[4], fbl[4];
#pragma unroll
        for (int j = 0; j < 4; ++j) {
            fbh[j] = *(const short8*)&BsH[buf][TILE_OFF(btile + j) + lane * 8];
            fbl[j] = *(const short8*)&BsL[buf][TILE_OFF(btile + j) + lane * 8];
        }

        short8 ah[2], al[2];
        if (buf) {
            cvt(y0, y1, ah[0], al[0]);
            cvt(y2, y3, ah[1], al[1]);
            if (ks + 2 < ksteps) lda(y0, y1, y2, y3, ks + 2);
        } else {
            cvt(x0, x1, ah[0], al[0]);
            cvt(x2, x3, ah[1], al[1]);
            if (ks + 2 < ksteps) lda(x0, x1, x2, x3, ks + 2);
        }

#pragma unroll
        for (int i = 0; i < 2; ++i)
#pragma unroll
            for (int j = 0; j < 4; ++j) {
                acc[i][j] = __builtin_amdgcn_mfma_f32_16x16x32_bf16(
                    ah[i], fbh[j], acc[i][j], 0, 0, 0);
                acc[i][j] = __builtin_amdgcn_mfma_f32_16x16x32_bf16(
                    ah[i], fbl[j], acc[i][j], 0, 0, 0);
                acc[i][j] = __builtin_amdgcn_mfma_f32_16x16x32_bf16(
                    al[i], fbh[j], acc[i][j], 0, 0, 0);
            }
    }

    // epilogue: C/D layout col=lane&15, row=quad*4+reg
#pragma unroll
    for (int i = 0; i < 2; ++i) {
#pragma unroll
        for (int r = 0; r < 4; ++r) {
            int gr = row0 + R + i * 16 + quad * 4 + r;
            if (gr < N) {
#pragma unroll
                for (int j = 0; j < 4; ++j)
                    C[(size_t)gr * 128 + c0 + j * 16 + m16] = acc[i][j][r];
            }
        }
    }
}

// ---- propagate (one wave per node, 128 feats = 2/lane), unroll x8 ---------
__global__ __launch_bounds__(256) void propagate_kernel(
    const float* __restrict__ h, const int* __restrict__ rowptr,
    const int* __restrict__ csr_src, const float* __restrict__ dis,
    const float* __restrict__ bias, float* __restrict__ out, int N, int do_relu) {
    int wave = (blockIdx.x * 256 + threadIdx.x) >> 6;
    int lane = threadIdx.x & 63;
    if (wave >= N) return;
    int v = wave;
    int f = lane * 2;
    float dv = dis[v];
    float ax = 0.f, ay = 0.f;
    int beg = rowptr[v], end = rowptr[v + 1];
    int i = beg;
    for (; i + 8 <= end; i += 8) {
        int s[8];
        float ww[8];
        float2 g[8];
#pragma unroll
        for (int u = 0; u < 8; ++u) s[u] = csr_src[i + u];
#pragma unroll
        for (int u = 0; u < 8; ++u) ww[u] = dis[s[u]];
#pragma unroll
        for (int u = 0; u < 8; ++u) g[u] = *(const float2*)&h[(size_t)s[u] * 128 + f];
#pragma unroll
        for (int u = 0; u < 8; ++u) {
            float t = ww[u] * dv;
            ax += t * g[u].x;
            ay += t * g[u].y;
        }
    }
    if (i + 4 <= end) {
        int s[4];
        float ww[4];
        float2 g[4];
#pragma unroll
        for (int u = 0; u < 4; ++u) s[u] = csr_src[i + u];
#pragma unroll
        for (int u = 0; u < 4; ++u) ww[u] = dis[s[u]];
#pragma unroll
        for (int u = 0; u < 4; ++u) g[u] = *(const float2*)&h[(size_t)s[u] * 128 + f];
#pragma unroll
        for (int u = 0; u < 4; ++u) {
            float t = ww[u] * dv;
            ax += t * g[u].x;
            ay += t * g[u].y;
        }
        i += 4;
    }
    for (; i < end; ++i) {
        int s = csr_src[i];
        float ws = dis[s] * dv;
        float2 g = *(const float2*)&h[(size_t)s * 128 + f];
        ax += ws * g.x;
        ay += ws * g.y;
    }
    float2 hv = *(const float2*)&h[(size_t)v * 128 + f];
    ax += dv * dv * hv.x;
    ay += dv * dv * hv.y;
    ax += bias[f];
    ay += bias[f + 1];
    if (do_relu) { ax = fmaxf(ax, 0.f); ay = fmaxf(ay, 0.f); }
    *(float2*)&out[(size_t)v * 128 + f] = make_float2(ax, ay);
}

// ---- final propagate: split into z_mean / z_log_std -----------------------
__global__ void __launch_bounds__(256) propagate_final_kernel(
    const float* __restrict__ h, const int* __restrict__ rowptr,
    const int* __restrict__ csr_src, const float* __restrict__ dis,
    const float* __restrict__ bm, const float* __restrict__ bs,
    float* __restrict__ out, int N) {
    int wave = (blockIdx.x * 256 + threadIdx.x) >> 6;
    int lane = threadIdx.x & 63;
    if (wave >= N) return;
    int v = wave;
    int f = lane * 2;
    float dv = dis[v];
    float ax = 0.f, ay = 0.f;
    int beg = rowptr[v], end = rowptr[v + 1];
    int i = beg;
    for (; i + 8 <= end; i += 8) {
        int s[8];
        float ww[8];
        float2 g[8];
#pragma unroll
        for (int u = 0; u < 8; ++u) s[u] = csr_src[i + u];
#pragma unroll
        for (int u = 0; u < 8; ++u) ww[u] = dis[s[u]];
#pragma unroll
        for (int u = 0; u < 8; ++u) g[u] = *(const float2*)&h[(size_t)s[u] * 128 + f];
#pragma unroll
        for (int u = 0; u < 8; ++u) {
            float t = ww[u] * dv;
            ax += t * g[u].x;
            ay += t * g[u].y;
        }
    }
    if (i + 4 <= end) {
        int s[4];
        float ww[4];
        float2 g[4];
#pragma unroll
        for (int u = 0; u < 4; ++u) s[u] = csr_src[i + u];
#pragma unroll
        for (int u = 0; u < 4; ++u) ww[u] = dis[s[u]];
#pragma unroll
        for (int u = 0; u < 4; ++u) g[u] = *(const float2*)&h[(size_t)s[u] * 128 + f];
#pragma unroll
        for (int u = 0; u < 4; ++u) {
            float t = ww[u] * dv;
            ax += t * g[u].x;
            ay += t * g[u].y;
        }
        i += 4;
    }
    for (; i < end; ++i) {
        int s = csr_src[i];
        float ws = dis[s] * dv;
        float2 g = *(const float2*)&h[(size_t)s * 128 + f];
        ax += ws * g.x;
        ay += ws * g.y;
    }
    float2 hv = *(const float2*)&h[(size_t)v * 128 + f];
    ax += dv * dv * hv.x;
    ay += dv * dv * hv.y;
    if (f < 64) {
        *(float2*)&out[(size_t)v * 64 + f] = make_float2(ax + bm[f], ay + bm[f + 1]);
    } else {
        int g = f - 64;
        *(float2*)&out[(size_t)N * 64 + (size_t)v * 64 + g] =
            make_float2(ax + bs[g], ay + bs[g + 1]);
    }
}

extern "C" void kernel_launch(void* const* d_in, const int* in_sizes, int n_in,
                              void* d_out, int out_size, void* d_ws, size_t ws_size,
                              hipStream_t stream) {
    const float* x  = (const float*)d_in[0];
    const int*   ew = (const int*)d_in[1];
    const float* W1 = (const float*)d_in[2];
    const float* b1 = (const float*)d_in[3];
    const float* W2 = (const float*)d_in[4];
    const float* b2 = (const float*)d_in[5];
    const float* Wm = (const float*)d_in[6];
    const float* bm = (const float*)d_in[7];
    const float* Ws = (const float*)d_in[8];
    const float* bs = (const float*)d_in[9];
    float* out = (float*)d_out;

    const int IN = 512, H = 128;
    const int N = in_sizes[0] / IN;     // 50000
    const int E = in_sizes[1] / 2;      // 800000

    // ---- workspace: ~55.6 MB total (< proven-safe 58.47 MB) ----------------
    char* base = (char*)d_ws;
    size_t off = 0;
    auto alloc = [&](size_t bytes) -> char* {
        char* p = base + off;
        off = (off + bytes + 255) & ~(size_t)255;
        return p;
    };
    char*  degcur  = (char*) alloc(400384);             // deg + cursor (zeroed)
    float* dis     = (float*)alloc((size_t)N * 4);
    int*   rowptr  = (int*)  alloc((size_t)(N + 1) * 4);
    int*   aux     = (int*)  alloc(256 * 4);
    int*   csr_src = (int*)  alloc((size_t)E * 4);
    u16*   W1t_hi  = (u16*)  alloc((size_t)IN * H * 2);
    u16*   W1t_lo  = (u16*)  alloc((size_t)IN * H * 2);
    u16*   W2t_hi  = (u16*)  alloc((size_t)H * H * 2);
    u16*   W2t_lo  = (u16*)  alloc((size_t)H * H * 2);
    u16*   Wct_hi  = (u16*)  alloc((size_t)H * H * 2);
    u16*   Wct_lo  = (u16*)  alloc((size_t)H * H * 2);
    float* hA      = (float*)alloc((size_t)N * H * 4);
    float* hB      = (float*)alloc((size_t)N * H * 4);
    (void)ws_size; (void)n_in; (void)out_size;

    int* deg    = (int*)degcur;
    int* cursor = (int*)(degcur + 200192);

    hipMemsetAsync(degcur, 0, 400384, stream);

    const int eblocks = (E + 255) / 256;
    const int nblocks = (N + 255) / 256;

    conv_all_kernel<<<(98304 + 255) / 256, 256, 0, stream>>>(
        W1, W2, Wm, Ws, W1t_hi, W1t_lo, W2t_hi, W2t_lo, Wct_hi, Wct_lo);
    deg_kernel<<<eblocks, 256, 0, stream>>>(ew, deg, E);
    scan_block_kernel<<<nblocks, 256, 0, stream>>>(deg, rowptr, aux, dis, N);
    scan_aux_kernel<<<1, 256, 0, stream>>>(aux, nblocks);
    add_offsets_kernel<<<nblocks, 256, 0, stream>>>(rowptr, aux, N, E);
    fill_csr_kernel<<<eblocks, 256, 0, stream>>>(ew, rowptr, cursor, csr_src, E);

    // GEMM: 64-row block tiles, 4 waves (2 row x 2 col sub-tiles)
    const int gblocks = (N + 63) / 64;
    const int pblocks = (N * 64 + 255) / 256;

    gemm_mfma<<<gblocks, 256, 0, stream>>>(x, W1t_hi, W1t_lo, hA, N, IN);
    propagate_kernel<<<pblocks, 256, 0, stream>>>(hA, rowptr, csr_src, dis,
                                                  b1, hB, N, 1);
    gemm_mfma<<<gblocks, 256, 0, stream>>>(hB, W2t_hi, W2t_lo, hA, N, H);
    propagate_kernel<<<pblocks, 256, 0, stream>>>(hA, rowptr, csr_src, dis,
                                                  b2, hB, N, 1);
    gemm_mfma<<<gblocks, 256, 0, stream>>>(hB, Wct_hi, Wct_lo, hA, N, H);
    propagate_final_kernel<<<pblocks, 256, 0, stream>>>(hA, rowptr, csr_src, dis,
                                                        bm, bs, out, N);
}